// Round 1
// baseline (1801.865 us; speedup 1.0000x reference)
//
#include <hip/hip_runtime.h>

using u16    = unsigned short;
using bf16x8 = __attribute__((ext_vector_type(8))) short;
using f32x4  = __attribute__((ext_vector_type(4))) float;
using u16x4  = __attribute__((ext_vector_type(4))) u16;

#define NB   16
#define PP   2048
#define CC   64
#define KK   16
#define MROWS (NB*PP*KK)   /* 524288 */
#define NPTS  (NB*PP)      /* 32768  */

__device__ __forceinline__ float b2f(u16 u) { return __uint_as_float(((unsigned)u) << 16); }
__device__ __forceinline__ u16 f2b(float f) {
  unsigned u = __float_as_uint(f);
  return (u16)((u + 0x7fffu + ((u >> 16) & 1u)) >> 16);
}

// ---------------- prep: features (N,C,P) -> X (N,P,C) fp32 + bf16, r = sum x^2 ----------------
__global__ __launch_bounds__(256) void prep_k(const float* __restrict__ F,
                                              float* __restrict__ X,
                                              u16* __restrict__ Xb,
                                              float* __restrict__ r) {
  int gidx = blockIdx.x * 256 + threadIdx.x;      // 0..32767
  int n = gidx >> 11, p = gidx & 2047;
  const float* src = F + (size_t)n * CC * PP + p;
  float v[CC];
  float rr = 0.f;
  #pragma unroll
  for (int c = 0; c < CC; ++c) { v[c] = src[(size_t)c * PP]; rr += v[c] * v[c]; }
  float* dst = X + (size_t)gidx * CC;
  #pragma unroll
  for (int c = 0; c < CC; c += 4) {
    float4 w; w.x = v[c]; w.y = v[c+1]; w.z = v[c+2]; w.w = v[c+3];
    *(float4*)(dst + c) = w;
  }
  u16* db = Xb + (size_t)gidx * CC;
  #pragma unroll
  for (int c = 0; c < CC; c += 8) {
    bf16x8 w8;
    #pragma unroll
    for (int j = 0; j < 8; ++j) w8[j] = (short)f2b(v[c + j]);
    *(bf16x8*)(db + c) = w8;
  }
  r[gidx] = rr;
}

// ---------------- weight fp32 -> bf16 ----------------
__global__ __launch_bounds__(256) void cvtw_k(const float* __restrict__ w0, const float* __restrict__ w1,
                                              const float* __restrict__ w2, const float* __restrict__ wsb,
                                              u16* __restrict__ b0, u16* __restrict__ b1,
                                              u16* __restrict__ b2, u16* __restrict__ bs) {
  int i = blockIdx.x * 256 + threadIdx.x;         // 20480 total
  if (i < 8192)        b0[i]          = f2b(w0[i]);
  else if (i < 12288)  b1[i - 8192]   = f2b(w1[i - 8192]);
  else if (i < 16384)  b2[i - 12288]  = f2b(w2[i - 12288]);
  else if (i < 20480)  bs[i - 16384]  = f2b(wsb[i - 16384]);
}

// ---------------- fused KNN: distances (fp32 GEMM in LDS) + streaming top-16 ----------------
__global__ __launch_bounds__(256) void knn_k(const float* __restrict__ X,
                                             const float* __restrict__ r,
                                             int* __restrict__ idx) {
  __shared__ float Xp[64][68];
  __shared__ float Xq[64][132];
  __shared__ float D[64][132];
  __shared__ float rq[128];
  __shared__ float dl[64][16];
  __shared__ int   il[64][16];

  const int n  = blockIdx.x >> 5;
  const int pb = (blockIdx.x & 31) * 64;
  const int t  = threadIdx.x;
  const float* Xn = X + (size_t)n * PP * CC;

  { // stage Xp transposed [c][p]
    const int pr = t & 63, qt = t >> 6;
    const float* src = Xn + (size_t)(pb + pr) * CC + qt * 16;
    #pragma unroll
    for (int j = 0; j < 16; j += 4) {
      float4 v = *(const float4*)(src + j);
      Xp[qt*16 + j + 0][pr] = v.x;
      Xp[qt*16 + j + 1][pr] = v.y;
      Xp[qt*16 + j + 2][pr] = v.z;
      Xp[qt*16 + j + 3][pr] = v.w;
    }
    if (t < 64) {
      #pragma unroll
      for (int s = 0; s < 16; ++s) { dl[t][s] = 3.0e38f; il[t][s] = 0; }
    }
  }

  const int ph = t >> 5;   // 0..7  (8 p's each)
  const int qh = t & 31;   // 0..31 (4 q's each)

  for (int qb = 0; qb < PP; qb += 128) {
    __syncthreads();
    { // stage Xq transposed [c][q] + rq
      const int qr = t & 127, hf = t >> 7;
      const float* src = Xn + (size_t)(qb + qr) * CC + hf * 32;
      #pragma unroll
      for (int j = 0; j < 32; j += 4) {
        float4 v = *(const float4*)(src + j);
        Xq[hf*32 + j + 0][qr] = v.x;
        Xq[hf*32 + j + 1][qr] = v.y;
        Xq[hf*32 + j + 2][qr] = v.z;
        Xq[hf*32 + j + 3][qr] = v.w;
      }
      if (t < 128) rq[t] = r[n * PP + qb + t];
    }
    __syncthreads();

    float acc[8][4];
    #pragma unroll
    for (int i = 0; i < 8; ++i)
      #pragma unroll
      for (int j = 0; j < 4; ++j) acc[i][j] = 0.f;

    #pragma unroll 4
    for (int c = 0; c < 64; ++c) {
      const float4 a0 = *(const float4*)&Xp[c][ph*8];
      const float4 a1 = *(const float4*)&Xp[c][ph*8 + 4];
      const float4 bq = *(const float4*)&Xq[c][qh*4];
      float av[8] = {a0.x, a0.y, a0.z, a0.w, a1.x, a1.y, a1.z, a1.w};
      float bv[4] = {bq.x, bq.y, bq.z, bq.w};
      #pragma unroll
      for (int i = 0; i < 8; ++i)
        #pragma unroll
        for (int j = 0; j < 4; ++j)
          acc[i][j] = fmaf(av[i], bv[j], acc[i][j]);
    }

    { // D = rq - 2*dot (ordering-equivalent to ref distance), self -> +big
      float rqv[4];
      #pragma unroll
      for (int j = 0; j < 4; ++j) rqv[j] = rq[qh*4 + j];
      #pragma unroll
      for (int i = 0; i < 8; ++i) {
        const int p = ph*8 + i;
        float d0 = rqv[0] - 2.f * acc[i][0]; if (qb + qh*4 + 0 == pb + p) d0 = 3.0e38f;
        float d1 = rqv[1] - 2.f * acc[i][1]; if (qb + qh*4 + 1 == pb + p) d1 = 3.0e38f;
        float d2 = rqv[2] - 2.f * acc[i][2]; if (qb + qh*4 + 2 == pb + p) d2 = 3.0e38f;
        float d3 = rqv[3] - 2.f * acc[i][3]; if (qb + qh*4 + 3 == pb + p) d3 = 3.0e38f;
        float4 dv; dv.x = d0; dv.y = d1; dv.z = d2; dv.w = d3;
        *(float4*)&D[p][qh*4] = dv;
      }
    }
    __syncthreads();

    if (t < 64) { // wave-0 streaming top-16 (stable: strict <, ascending scan)
      const int p = t;
      float th = dl[p][15];
      #pragma unroll 1
      for (int j4 = 0; j4 < 128; j4 += 4) {
        const float4 dv = *(const float4*)&D[p][j4];
        #pragma unroll
        for (int u = 0; u < 4; ++u) {
          const float d = (u == 0) ? dv.x : (u == 1) ? dv.y : (u == 2) ? dv.z : dv.w;
          if (d < th) {
            const int qi = qb + j4 + u;
            bool placed = false;
            #pragma unroll
            for (int s = 15; s >= 1; --s) {
              const float ps = dl[p][s-1]; const int pi = il[p][s-1];
              if (!placed) {
                if (d < ps) { dl[p][s] = ps; il[p][s] = pi; }
                else        { dl[p][s] = d;  il[p][s] = qi; placed = true; }
              }
            }
            if (!placed) { dl[p][0] = d; il[p][0] = qi; }
            th = dl[p][15];
          }
        }
      }
    }
  }

  if (t < 64) {
    #pragma unroll
    for (int s = 0; s < 16; ++s)
      idx[((size_t)n * PP + pb + t) * KK + s] = il[t][s];
  }
}

// ---------------- conv (MFMA bf16): y = A @ w^T + bias ----------------
// GATHER: A rows built from Xb + idx ([fc, fc-f]); BNRELU: A = relu(in*s+t) from st.
template<int KIN, bool GATHER, bool BNRELU>
__global__ __launch_bounds__(256) void conv_k(const u16* __restrict__ in,
                                              const int* __restrict__ idxp,
                                              const u16* __restrict__ wb,
                                              const float* __restrict__ bias,
                                              const float* __restrict__ st,
                                              u16* __restrict__ yout) {
  constexpr int NKB = KIN / 32;
  const int t = threadIdx.x;
  const int wv = t >> 6, l = t & 63, hi = l >> 4, lo = l & 15;
  const int rbase = blockIdx.x * 256 + wv * 64;

  bf16x8 wf[4][NKB];
  #pragma unroll
  for (int ob = 0; ob < 4; ++ob)
    #pragma unroll
    for (int kb = 0; kb < NKB; ++kb)
      wf[ob][kb] = *(const bf16x8*)(wb + (size_t)(ob*16 + lo) * KIN + kb*32 + hi*8);

  int qv[4];
  if constexpr (GATHER) {
    #pragma unroll
    for (int rb = 0; rb < 4; ++rb) {
      const int g = (rbase + rb*16) >> 4;     // one point per 16-row block
      qv[rb] = idxp[g * KK + lo];
    }
  }

  f32x4 acc[4][4];
  #pragma unroll
  for (int a = 0; a < 4; ++a)
    #pragma unroll
    for (int b = 0; b < 4; ++b) { f32x4 z = {0.f, 0.f, 0.f, 0.f}; acc[a][b] = z; }

  #pragma unroll
  for (int kb = 0; kb < NKB; ++kb) {
    float sv[8], tv[8];
    if constexpr (BNRELU) {
      const int k0 = kb*32 + hi*8;
      *(float4*)&sv[0] = *(const float4*)(st + k0);
      *(float4*)&sv[4] = *(const float4*)(st + k0 + 4);
      *(float4*)&tv[0] = *(const float4*)(st + KIN + k0);
      *(float4*)&tv[4] = *(const float4*)(st + KIN + k0 + 4);
    }
    bf16x8 af[4];
    #pragma unroll
    for (int rb = 0; rb < 4; ++rb) {
      if constexpr (GATHER) {
        const int g  = (rbase + rb*16) >> 4;
        const int k0 = kb*32 + hi*8;
        const bf16x8 fc = *(const bf16x8*)(in + (size_t)g * CC + (k0 & 63));
        if (kb < 2) {
          af[rb] = fc;                                   // h[:, :64] = fc (broadcast rows)
        } else {
          const int nn = g >> 11;
          const bf16x8 fv = *(const bf16x8*)(in + (size_t)(nn * PP + qv[rb]) * CC + (k0 & 63));
          bf16x8 df;
          #pragma unroll
          for (int j = 0; j < 8; ++j)
            df[j] = (short)f2b(b2f((u16)fc[j]) - b2f((u16)fv[j]));
          af[rb] = df;
        }
      } else {
        const int row = rbase + rb*16 + lo;
        const bf16x8 rv = *(const bf16x8*)(in + (size_t)row * KIN + kb*32 + hi*8);
        if constexpr (BNRELU) {
          bf16x8 tr;
          #pragma unroll
          for (int j = 0; j < 8; ++j) {
            const float x = fmaxf(b2f((u16)rv[j]) * sv[j] + tv[j], 0.f);
            tr[j] = (short)f2b(x);
          }
          af[rb] = tr;
        } else {
          af[rb] = rv;
        }
      }
    }
    #pragma unroll
    for (int ob = 0; ob < 4; ++ob)
      #pragma unroll
      for (int rb = 0; rb < 4; ++rb)
        acc[rb][ob] = __builtin_amdgcn_mfma_f32_16x16x32_bf16(wf[ob][kb], af[rb], acc[rb][ob], 0, 0, 0);
  }

  // epilogue: D[row=(l>>4)*4+reg -> out ch][col=l&15 -> A row]; contiguous 4xbf16 store
  #pragma unroll
  for (int ob = 0; ob < 4; ++ob) {
    const int o0 = ob*16 + hi*4;
    const float4 bv = *(const float4*)(bias + o0);
    #pragma unroll
    for (int rb = 0; rb < 4; ++rb) {
      const int row = rbase + rb*16 + lo;
      u16x4 pk;
      pk[0] = f2b(acc[rb][ob][0] + bv.x);
      pk[1] = f2b(acc[rb][ob][1] + bv.y);
      pk[2] = f2b(acc[rb][ob][2] + bv.z);
      pk[3] = f2b(acc[rb][ob][3] + bv.w);
      *(u16x4*)(yout + (size_t)row * CC + o0) = pk;
    }
  }
}

// ---------------- per-block channel sum/sumsq partials ----------------
__global__ __launch_bounds__(256) void stats_k(const u16* __restrict__ y,
                                               float* __restrict__ partials, int M) {
  __shared__ float red[256][17];
  const int t = threadIdx.x, b = blockIdx.x;
  const int rpw = M >> 9;                 // rows per workgroup (grid = 512)
  const int c0 = (t & 7) * 8;
  float sm[8], sq[8];
  #pragma unroll
  for (int j = 0; j < 8; ++j) { sm[j] = 0.f; sq[j] = 0.f; }
  const int iters = rpw >> 5;
  for (int i = 0; i < iters; ++i) {
    const int row = b * rpw + (t >> 3) + i * 32;
    const bf16x8 v = *(const bf16x8*)(y + (size_t)row * CC + c0);
    #pragma unroll
    for (int j = 0; j < 8; ++j) { const float x = b2f((u16)v[j]); sm[j] += x; sq[j] += x * x; }
  }
  #pragma unroll
  for (int j = 0; j < 8; ++j) { red[t][j] = sm[j]; red[t][8 + j] = sq[j]; }
  __syncthreads();
  for (int s = 128; s >= 8; s >>= 1) {
    if (t < s) {
      #pragma unroll
      for (int j = 0; j < 16; ++j) red[t][j] += red[t + s][j];
    }
    __syncthreads();
  }
  if (t < 8) {
    #pragma unroll
    for (int j = 0; j < 8; ++j) {
      partials[b * 128 + t * 8 + j]      = red[t][j];
      partials[b * 128 + 64 + t * 8 + j] = red[t][8 + j];
    }
  }
}

// ---------------- reduce partials -> fused BN scale/bias ----------------
__global__ __launch_bounds__(256) void red_k(const float* __restrict__ partials,
                                             const float* __restrict__ g,
                                             const float* __restrict__ be,
                                             float* __restrict__ st, float invM) {
  __shared__ float buf[4][64][2];
  const int t = threadIdx.x, c = t & 63, sl = t >> 6;
  float s = 0.f, q = 0.f;
  for (int w = sl * 128; w < sl * 128 + 128; ++w) {
    s += partials[w * 128 + c];
    q += partials[w * 128 + 64 + c];
  }
  buf[sl][c][0] = s; buf[sl][c][1] = q;
  __syncthreads();
  if (t < 64) {
    const float S = buf[0][t][0] + buf[1][t][0] + buf[2][t][0] + buf[3][t][0];
    const float Q = buf[0][t][1] + buf[1][t][1] + buf[2][t][1] + buf[3][t][1];
    const float m = S * invM;
    const float v = fmaxf(Q * invM - m * m, 0.f);
    const float sc = g[t] * rsqrtf(v + 1e-5f);
    st[t] = sc;
    st[64 + t] = be[t] - m * sc;
  }
}

// ---------------- final: bn2+relu, mean over K, + bn(shortcut), relu, (N,C,P) store ----------------
__global__ __launch_bounds__(256) void final_k(const u16* __restrict__ y2,
                                               const u16* __restrict__ ysc,
                                               const float* __restrict__ st2,
                                               const float* __restrict__ stS,
                                               float* __restrict__ out) {
  __shared__ float ot[64][68];
  const int b = blockIdx.x, t = threadIdx.x;
  const int n = b >> 5, p0 = (b & 31) * 64;
  const int phh = t >> 2, jh = t & 3, c0 = jh * 16;
  const int g = n * PP + p0 + phh;
  float acc[16];
  #pragma unroll
  for (int i = 0; i < 16; ++i) acc[i] = 0.f;
  float sv[16], tv[16];
  #pragma unroll
  for (int i = 0; i < 16; ++i) { sv[i] = st2[c0 + i]; tv[i] = st2[64 + c0 + i]; }
  for (int k = 0; k < KK; ++k) {
    const u16* rp = y2 + ((size_t)g * KK + k) * CC + c0;
    const bf16x8 v0 = *(const bf16x8*)rp;
    const bf16x8 v1 = *(const bf16x8*)(rp + 8);
    #pragma unroll
    for (int j = 0; j < 8; ++j) {
      acc[j]     += fmaxf(b2f((u16)v0[j]) * sv[j]     + tv[j],     0.f);
      acc[8 + j] += fmaxf(b2f((u16)v1[j]) * sv[8 + j] + tv[8 + j], 0.f);
    }
  }
  const u16* sp = ysc + (size_t)g * CC + c0;
  const bf16x8 s0 = *(const bf16x8*)sp;
  const bf16x8 s1 = *(const bf16x8*)(sp + 8);
  #pragma unroll
  for (int i = 0; i < 16; ++i) {
    const float scx = b2f((u16)(i < 8 ? s0[i] : s1[i - 8])) * stS[c0 + i] + stS[64 + c0 + i];
    ot[c0 + i][phh] = fmaxf(acc[i] * (1.f / 16.f) + scx, 0.f);
  }
  __syncthreads();
  const int c = t >> 2, pc = t & 3;
  const float* src = &ot[c][pc * 16];
  float* dst = out + (size_t)n * CC * PP + (size_t)c * PP + p0 + pc * 16;
  #pragma unroll
  for (int j = 0; j < 16; j += 4) *(float4*)(dst + j) = *(const float4*)(src + j);
}

// ---------------- host ----------------
extern "C" void kernel_launch(void* const* d_in, const int* in_sizes, int n_in,
                              void* d_out, int out_size, void* d_ws, size_t ws_size,
                              hipStream_t stream) {
  (void)in_sizes; (void)n_in; (void)out_size; (void)ws_size;
  const float* F   = (const float*)d_in[0];
  const float* w0  = (const float*)d_in[1];
  const float* b0  = (const float*)d_in[2];
  const float* g0  = (const float*)d_in[3];
  const float* be0 = (const float*)d_in[4];
  const float* w1  = (const float*)d_in[5];
  const float* b1  = (const float*)d_in[6];
  const float* g1  = (const float*)d_in[7];
  const float* be1 = (const float*)d_in[8];
  const float* w2  = (const float*)d_in[9];
  const float* b2  = (const float*)d_in[10];
  const float* g2  = (const float*)d_in[11];
  const float* be2 = (const float*)d_in[12];
  const float* wS  = (const float*)d_in[13];
  const float* bS  = (const float*)d_in[14];
  const float* gS  = (const float*)d_in[15];
  const float* beS = (const float*)d_in[16];

  char* ws = (char*)d_ws;
  size_t off = 0;
  auto carve = [&](size_t bytes) -> void* {
    void* p = ws + off;
    off += (bytes + 255) & ~(size_t)255;
    return p;
  };
  float* X        = (float*)carve((size_t)NPTS * CC * 4);       // 8.4 MB
  u16*   Xb       = (u16*)  carve((size_t)NPTS * CC * 2);       // 4.2 MB
  float* rr       = (float*)carve((size_t)NPTS * 4);            // 128 KB
  int*   idx      = (int*)  carve((size_t)NPTS * KK * 4);       // 2 MB
  u16*   wb0      = (u16*)  carve(8192 * 2);
  u16*   wb1      = (u16*)  carve(4096 * 2);
  u16*   wb2      = (u16*)  carve(4096 * 2);
  u16*   wbs      = (u16*)  carve(4096 * 2);
  u16*   y        = (u16*)  carve((size_t)MROWS * CC * 2);      // 67 MB
  u16*   ysc      = (u16*)  carve((size_t)NPTS * CC * 2);       // 4.2 MB
  float* partials = (float*)carve(512 * 128 * 4);               // 256 KB
  float* st0      = (float*)carve(128 * 4);
  float* st1      = (float*)carve(128 * 4);
  float* st2      = (float*)carve(128 * 4);
  float* stS      = (float*)carve(128 * 4);

  prep_k<<<NPTS / 256, 256, 0, stream>>>(F, X, Xb, rr);
  cvtw_k<<<80, 256, 0, stream>>>(w0, w1, w2, wS, wb0, wb1, wb2, wbs);
  knn_k<<<NB * (PP / 64), 256, 0, stream>>>(X, rr, idx);

  conv_k<128, true,  false><<<MROWS / 256, 256, 0, stream>>>(Xb, idx, wb0, b0, nullptr, y);
  stats_k<<<512, 256, 0, stream>>>(y, partials, MROWS);
  red_k<<<1, 256, 0, stream>>>(partials, g0, be0, st0, 1.f / (float)MROWS);

  conv_k<64, false, true><<<MROWS / 256, 256, 0, stream>>>(y, nullptr, wb1, b1, st0, y);
  stats_k<<<512, 256, 0, stream>>>(y, partials, MROWS);
  red_k<<<1, 256, 0, stream>>>(partials, g1, be1, st1, 1.f / (float)MROWS);

  conv_k<64, false, true><<<MROWS / 256, 256, 0, stream>>>(y, nullptr, wb2, b2, st1, y);
  stats_k<<<512, 256, 0, stream>>>(y, partials, MROWS);
  red_k<<<1, 256, 0, stream>>>(partials, g2, be2, st2, 1.f / (float)MROWS);

  conv_k<64, false, false><<<NPTS / 256, 256, 0, stream>>>(Xb, nullptr, wbs, bS, nullptr, ysc);
  stats_k<<<512, 256, 0, stream>>>(ysc, partials, NPTS);
  red_k<<<1, 256, 0, stream>>>(partials, gS, beS, stS, 1.f / (float)NPTS);

  final_k<<<NB * (PP / 64), 256, 0, stream>>>(y, ysc, st2, stS, (float*)d_out);
}

// Round 2
// 677.809 us; speedup vs baseline: 2.6584x; 2.6584x over previous
//
#include <hip/hip_runtime.h>

using u16    = unsigned short;
using bf16x8 = __attribute__((ext_vector_type(8))) short;
using f32x4  = __attribute__((ext_vector_type(4))) float;
using u16x4  = __attribute__((ext_vector_type(4))) u16;

#define NB   16
#define PP   2048
#define CC   64
#define KK   16
#define MROWS (NB*PP*KK)   /* 524288 */
#define NPTS  (NB*PP)      /* 32768  */

__device__ __forceinline__ float b2f(u16 u) { return __uint_as_float(((unsigned)u) << 16); }
__device__ __forceinline__ u16 f2b(float f) {
  unsigned u = __float_as_uint(f);
  return (u16)((u + 0x7fffu + ((u >> 16) & 1u)) >> 16);
}

// ---------------- prep: features (N,C,P) -> X (N,P,C) fp32 + bf16, r = sum x^2 ----------------
__global__ __launch_bounds__(256) void prep_k(const float* __restrict__ F,
                                              float* __restrict__ X,
                                              u16* __restrict__ Xb,
                                              float* __restrict__ r) {
  int gidx = blockIdx.x * 256 + threadIdx.x;      // 0..32767
  int n = gidx >> 11, p = gidx & 2047;
  const float* src = F + (size_t)n * CC * PP + p;
  float v[CC];
  float rr = 0.f;
  #pragma unroll
  for (int c = 0; c < CC; ++c) { v[c] = src[(size_t)c * PP]; rr += v[c] * v[c]; }
  float* dst = X + (size_t)gidx * CC;
  #pragma unroll
  for (int c = 0; c < CC; c += 4) {
    float4 w; w.x = v[c]; w.y = v[c+1]; w.z = v[c+2]; w.w = v[c+3];
    *(float4*)(dst + c) = w;
  }
  u16* db = Xb + (size_t)gidx * CC;
  #pragma unroll
  for (int c = 0; c < CC; c += 8) {
    bf16x8 w8;
    #pragma unroll
    for (int j = 0; j < 8; ++j) w8[j] = (short)f2b(v[c + j]);
    *(bf16x8*)(db + c) = w8;
  }
  r[gidx] = rr;
}

// ---------------- weight fp32 -> bf16 ----------------
__global__ __launch_bounds__(256) void cvtw_k(const float* __restrict__ w0, const float* __restrict__ w1,
                                              const float* __restrict__ w2, const float* __restrict__ wsb,
                                              u16* __restrict__ b0, u16* __restrict__ b1,
                                              u16* __restrict__ b2, u16* __restrict__ bs) {
  int i = blockIdx.x * 256 + threadIdx.x;         // 20480 total
  if (i < 8192)        b0[i]          = f2b(w0[i]);
  else if (i < 12288)  b1[i - 8192]   = f2b(w1[i - 8192]);
  else if (i < 16384)  b2[i - 12288]  = f2b(w2[i - 12288]);
  else if (i < 20480)  bs[i - 16384]  = f2b(wsb[i - 16384]);
}

// ---------------- branchless register top-16 insert (sorted ascending, stable) ----------------
__device__ __forceinline__ void ins16(float (&dl)[16], int (&il)[16], float d, int qi) {
  if (d < dl[15]) {
    #pragma unroll
    for (int s = 15; s >= 1; --s) {
      const bool sh_ = dl[s-1] > d;     // slot s-1 shifts down to s
      const bool me  = dl[s]   > d;     // d lands at s (first slot where dl[s] > d)
      dl[s] = sh_ ? dl[s-1] : (me ? d  : dl[s]);
      il[s] = sh_ ? il[s-1] : (me ? qi : il[s]);
    }
    if (dl[0] > d) { dl[0] = d; il[0] = qi; }
  }
}

// ---------------- fused KNN v2: per-thread register GEMM + register top-16 ----------------
// WG(256) owns 64 p-rows; thread t: row = pb + (t&63), scans quarter (t>>6) of each 128-q tile.
__global__ __launch_bounds__(256) void knn_k(const float* __restrict__ X,
                                             const float* __restrict__ r,
                                             int* __restrict__ idx) {
  __shared__ float sbuf[8704];          // Xq tile [128][68] (34 KB); reused for merge

  const int n    = blockIdx.x >> 5;
  const int pb   = (blockIdx.x & 31) * 64;
  const int t    = threadIdx.x;
  const int prow = pb + (t & 63);
  const int qh   = t >> 6;              // wave-uniform quarter index
  const float* Xn = X + (size_t)n * PP * CC;
  const float* rb = r + (size_t)n * PP;

  // own row into registers
  float xp[CC];
  {
    const float* xpr = Xn + (size_t)prow * CC;
    #pragma unroll
    for (int c = 0; c < CC; c += 4) {
      const float4 v = *(const float4*)(xpr + c);
      xp[c] = v.x; xp[c+1] = v.y; xp[c+2] = v.z; xp[c+3] = v.w;
    }
  }

  float dl[16]; int il[16];
  #pragma unroll
  for (int s = 0; s < 16; ++s) { dl[s] = 3.0e38f; il[s] = 0; }

  #pragma unroll 1
  for (int qb = 0; qb < PP; qb += 128) {
    __syncthreads();
    { // stage Xq tile [128][68]
      const int qr = t >> 1, chh = (t & 1) * 32;
      float* dstl = &sbuf[(size_t)qr * 68 + chh];
      const float* srcg = Xn + (size_t)(qb + qr) * CC + chh;
      #pragma unroll
      for (int j = 0; j < 32; j += 4)
        *(float4*)(dstl + j) = *(const float4*)(srcg + j);
    }
    __syncthreads();

    #pragma unroll 1
    for (int blk = 0; blk < 8; ++blk) {
      const int q0 = qh * 32 + blk * 4;         // within tile; wave-uniform
      const float* bq = &sbuf[(size_t)q0 * 68];
      float a0 = 0.f, a1 = 0.f, a2 = 0.f, a3 = 0.f;
      #pragma unroll
      for (int c = 0; c < CC; c += 4) {
        const float4 v0 = *(const float4*)(bq + c);
        const float4 v1 = *(const float4*)(bq + 68 + c);
        const float4 v2 = *(const float4*)(bq + 136 + c);
        const float4 v3 = *(const float4*)(bq + 204 + c);
        a0 = fmaf(xp[c], v0.x, a0); a0 = fmaf(xp[c+1], v0.y, a0);
        a0 = fmaf(xp[c+2], v0.z, a0); a0 = fmaf(xp[c+3], v0.w, a0);
        a1 = fmaf(xp[c], v1.x, a1); a1 = fmaf(xp[c+1], v1.y, a1);
        a1 = fmaf(xp[c+2], v1.z, a1); a1 = fmaf(xp[c+3], v1.w, a1);
        a2 = fmaf(xp[c], v2.x, a2); a2 = fmaf(xp[c+1], v2.y, a2);
        a2 = fmaf(xp[c+2], v2.z, a2); a2 = fmaf(xp[c+3], v2.w, a2);
        a3 = fmaf(xp[c], v3.x, a3); a3 = fmaf(xp[c+1], v3.y, a3);
        a3 = fmaf(xp[c+2], v3.z, a3); a3 = fmaf(xp[c+3], v3.w, a3);
      }
      const int qg = qb + q0;
      const float4 rv = *(const float4*)(rb + qg);
      float d0 = rv.x - 2.f * a0; if (qg + 0 == prow) d0 = 3.0e38f;
      float d1 = rv.y - 2.f * a1; if (qg + 1 == prow) d1 = 3.0e38f;
      float d2 = rv.z - 2.f * a2; if (qg + 2 == prow) d2 = 3.0e38f;
      float d3 = rv.w - 2.f * a3; if (qg + 3 == prow) d3 = 3.0e38f;
      const float m4 = fminf(fminf(d0, d1), fminf(d2, d3));
      if (m4 < dl[15]) {
        ins16(dl, il, d0, qg + 0);
        ins16(dl, il, d1, qg + 1);
        ins16(dl, il, d2, qg + 2);
        ins16(dl, il, d3, qg + 3);
      }
    }
  }

  // merge 4 partial top-16s per row (threads t, t+64, t+128, t+192)
  __syncthreads();
  {
    int* ibuf = (int*)sbuf;
    #pragma unroll
    for (int s = 0; s < 16; ++s) {
      sbuf[s * 256 + t]        = dl[s];     // conflict-free: lanes consecutive
      ibuf[4096 + s * 256 + t] = il[s];
    }
  }
  __syncthreads();
  if (t < 64) {
    const int* ibuf = (const int*)sbuf;
    #pragma unroll 1
    for (int j = 1; j < 4; ++j) {
      #pragma unroll 1
      for (int s = 0; s < 16; ++s) {
        const float d = sbuf[s * 256 + (t + 64 * j)];
        const int  qi = ibuf[4096 + s * 256 + (t + 64 * j)];
        ins16(dl, il, d, qi);
      }
    }
    #pragma unroll
    for (int s = 0; s < 16; ++s)
      idx[((size_t)n * PP + prow) * KK + s] = il[s];
  }
}

// ---------------- conv (MFMA bf16): y = A @ w^T + bias ----------------
// GATHER: A rows built from Xb + idx ([fc, fc-f]); BNRELU: A = relu(in*s+t) from st.
template<int KIN, bool GATHER, bool BNRELU>
__global__ __launch_bounds__(256) void conv_k(const u16* __restrict__ in,
                                              const int* __restrict__ idxp,
                                              const u16* __restrict__ wb,
                                              const float* __restrict__ bias,
                                              const float* __restrict__ st,
                                              u16* __restrict__ yout) {
  constexpr int NKB = KIN / 32;
  const int t = threadIdx.x;
  const int wv = t >> 6, l = t & 63, hi = l >> 4, lo = l & 15;
  const int rbase = blockIdx.x * 256 + wv * 64;

  bf16x8 wf[4][NKB];
  #pragma unroll
  for (int ob = 0; ob < 4; ++ob)
    #pragma unroll
    for (int kb = 0; kb < NKB; ++kb)
      wf[ob][kb] = *(const bf16x8*)(wb + (size_t)(ob*16 + lo) * KIN + kb*32 + hi*8);

  int qv[4];
  if constexpr (GATHER) {
    #pragma unroll
    for (int rb = 0; rb < 4; ++rb) {
      const int g = (rbase + rb*16) >> 4;     // one point per 16-row block
      qv[rb] = idxp[g * KK + lo];
    }
  }

  f32x4 acc[4][4];
  #pragma unroll
  for (int a = 0; a < 4; ++a)
    #pragma unroll
    for (int b = 0; b < 4; ++b) { f32x4 z = {0.f, 0.f, 0.f, 0.f}; acc[a][b] = z; }

  #pragma unroll
  for (int kb = 0; kb < NKB; ++kb) {
    float sv[8], tv[8];
    if constexpr (BNRELU) {
      const int k0 = kb*32 + hi*8;
      *(float4*)&sv[0] = *(const float4*)(st + k0);
      *(float4*)&sv[4] = *(const float4*)(st + k0 + 4);
      *(float4*)&tv[0] = *(const float4*)(st + KIN + k0);
      *(float4*)&tv[4] = *(const float4*)(st + KIN + k0 + 4);
    }
    bf16x8 af[4];
    #pragma unroll
    for (int rb = 0; rb < 4; ++rb) {
      if constexpr (GATHER) {
        const int g  = (rbase + rb*16) >> 4;
        const int k0 = kb*32 + hi*8;
        const bf16x8 fc = *(const bf16x8*)(in + (size_t)g * CC + (k0 & 63));
        if (kb < 2) {
          af[rb] = fc;                                   // h[:, :64] = fc (broadcast rows)
        } else {
          const int nn = g >> 11;
          const bf16x8 fv = *(const bf16x8*)(in + (size_t)(nn * PP + qv[rb]) * CC + (k0 & 63));
          bf16x8 df;
          #pragma unroll
          for (int j = 0; j < 8; ++j)
            df[j] = (short)f2b(b2f((u16)fc[j]) - b2f((u16)fv[j]));
          af[rb] = df;
        }
      } else {
        const int row = rbase + rb*16 + lo;
        const bf16x8 rv = *(const bf16x8*)(in + (size_t)row * KIN + kb*32 + hi*8);
        if constexpr (BNRELU) {
          bf16x8 tr;
          #pragma unroll
          for (int j = 0; j < 8; ++j) {
            const float x = fmaxf(b2f((u16)rv[j]) * sv[j] + tv[j], 0.f);
            tr[j] = (short)f2b(x);
          }
          af[rb] = tr;
        } else {
          af[rb] = rv;
        }
      }
    }
    #pragma unroll
    for (int ob = 0; ob < 4; ++ob)
      #pragma unroll
      for (int rb = 0; rb < 4; ++rb)
        acc[rb][ob] = __builtin_amdgcn_mfma_f32_16x16x32_bf16(wf[ob][kb], af[rb], acc[rb][ob], 0, 0, 0);
  }

  // epilogue: D[row=(l>>4)*4+reg -> out ch][col=l&15 -> A row]; contiguous 4xbf16 store
  #pragma unroll
  for (int ob = 0; ob < 4; ++ob) {
    const int o0 = ob*16 + hi*4;
    const float4 bv = *(const float4*)(bias + o0);
    #pragma unroll
    for (int rb = 0; rb < 4; ++rb) {
      const int row = rbase + rb*16 + lo;
      u16x4 pk;
      pk[0] = f2b(acc[rb][ob][0] + bv.x);
      pk[1] = f2b(acc[rb][ob][1] + bv.y);
      pk[2] = f2b(acc[rb][ob][2] + bv.z);
      pk[3] = f2b(acc[rb][ob][3] + bv.w);
      *(u16x4*)(yout + (size_t)row * CC + o0) = pk;
    }
  }
}

// ---------------- per-block channel sum/sumsq partials ----------------
__global__ __launch_bounds__(256) void stats_k(const u16* __restrict__ y,
                                               float* __restrict__ partials, int M) {
  __shared__ float red[256][17];
  const int t = threadIdx.x, b = blockIdx.x;
  const int rpw = M >> 9;                 // rows per workgroup (grid = 512)
  const int c0 = (t & 7) * 8;
  float sm[8], sq[8];
  #pragma unroll
  for (int j = 0; j < 8; ++j) { sm[j] = 0.f; sq[j] = 0.f; }
  const int iters = rpw >> 5;
  for (int i = 0; i < iters; ++i) {
    const int row = b * rpw + (t >> 3) + i * 32;
    const bf16x8 v = *(const bf16x8*)(y + (size_t)row * CC + c0);
    #pragma unroll
    for (int j = 0; j < 8; ++j) { const float x = b2f((u16)v[j]); sm[j] += x; sq[j] += x * x; }
  }
  #pragma unroll
  for (int j = 0; j < 8; ++j) { red[t][j] = sm[j]; red[t][8 + j] = sq[j]; }
  __syncthreads();
  for (int s = 128; s >= 8; s >>= 1) {
    if (t < s) {
      #pragma unroll
      for (int j = 0; j < 16; ++j) red[t][j] += red[t + s][j];
    }
    __syncthreads();
  }
  if (t < 8) {
    #pragma unroll
    for (int j = 0; j < 8; ++j) {
      partials[b * 128 + t * 8 + j]      = red[t][j];
      partials[b * 128 + 64 + t * 8 + j] = red[t][8 + j];
    }
  }
}

// ---------------- reduce partials -> fused BN scale/bias ----------------
__global__ __launch_bounds__(256) void red_k(const float* __restrict__ partials,
                                             const float* __restrict__ g,
                                             const float* __restrict__ be,
                                             float* __restrict__ st, float invM) {
  __shared__ float buf[4][64][2];
  const int t = threadIdx.x, c = t & 63, sl = t >> 6;
  float s = 0.f, q = 0.f;
  for (int w = sl * 128; w < sl * 128 + 128; ++w) {
    s += partials[w * 128 + c];
    q += partials[w * 128 + 64 + c];
  }
  buf[sl][c][0] = s; buf[sl][c][1] = q;
  __syncthreads();
  if (t < 64) {
    const float S = buf[0][t][0] + buf[1][t][0] + buf[2][t][0] + buf[3][t][0];
    const float Q = buf[0][t][1] + buf[1][t][1] + buf[2][t][1] + buf[3][t][1];
    const float m = S * invM;
    const float v = fmaxf(Q * invM - m * m, 0.f);
    const float sc = g[t] * rsqrtf(v + 1e-5f);
    st[t] = sc;
    st[64 + t] = be[t] - m * sc;
  }
}

// ---------------- final: bn2+relu, mean over K, + bn(shortcut), relu, (N,C,P) store ----------------
__global__ __launch_bounds__(256) void final_k(const u16* __restrict__ y2,
                                               const u16* __restrict__ ysc,
                                               const float* __restrict__ st2,
                                               const float* __restrict__ stS,
                                               float* __restrict__ out) {
  __shared__ float ot[64][68];
  const int b = blockIdx.x, t = threadIdx.x;
  const int n = b >> 5, p0 = (b & 31) * 64;
  const int phh = t >> 2, jh = t & 3, c0 = jh * 16;
  const int g = n * PP + p0 + phh;
  float acc[16];
  #pragma unroll
  for (int i = 0; i < 16; ++i) acc[i] = 0.f;
  float sv[16], tv[16];
  #pragma unroll
  for (int i = 0; i < 16; ++i) { sv[i] = st2[c0 + i]; tv[i] = st2[64 + c0 + i]; }
  for (int k = 0; k < KK; ++k) {
    const u16* rp = y2 + ((size_t)g * KK + k) * CC + c0;
    const bf16x8 v0 = *(const bf16x8*)rp;
    const bf16x8 v1 = *(const bf16x8*)(rp + 8);
    #pragma unroll
    for (int j = 0; j < 8; ++j) {
      acc[j]     += fmaxf(b2f((u16)v0[j]) * sv[j]     + tv[j],     0.f);
      acc[8 + j] += fmaxf(b2f((u16)v1[j]) * sv[8 + j] + tv[8 + j], 0.f);
    }
  }
  const u16* sp = ysc + (size_t)g * CC + c0;
  const bf16x8 s0 = *(const bf16x8*)sp;
  const bf16x8 s1 = *(const bf16x8*)(sp + 8);
  #pragma unroll
  for (int i = 0; i < 16; ++i) {
    const float scx = b2f((u16)(i < 8 ? s0[i] : s1[i - 8])) * stS[c0 + i] + stS[64 + c0 + i];
    ot[c0 + i][phh] = fmaxf(acc[i] * (1.f / 16.f) + scx, 0.f);
  }
  __syncthreads();
  const int c = t >> 2, pc = t & 3;
  const float* src = &ot[c][pc * 16];
  float* dst = out + (size_t)n * CC * PP + (size_t)c * PP + p0 + pc * 16;
  #pragma unroll
  for (int j = 0; j < 16; j += 4) *(float4*)(dst + j) = *(const float4*)(src + j);
}

// ---------------- host ----------------
extern "C" void kernel_launch(void* const* d_in, const int* in_sizes, int n_in,
                              void* d_out, int out_size, void* d_ws, size_t ws_size,
                              hipStream_t stream) {
  (void)in_sizes; (void)n_in; (void)out_size; (void)ws_size;
  const float* F   = (const float*)d_in[0];
  const float* w0  = (const float*)d_in[1];
  const float* b0  = (const float*)d_in[2];
  const float* g0  = (const float*)d_in[3];
  const float* be0 = (const float*)d_in[4];
  const float* w1  = (const float*)d_in[5];
  const float* b1  = (const float*)d_in[6];
  const float* g1  = (const float*)d_in[7];
  const float* be1 = (const float*)d_in[8];
  const float* w2  = (const float*)d_in[9];
  const float* b2  = (const float*)d_in[10];
  const float* g2  = (const float*)d_in[11];
  const float* be2 = (const float*)d_in[12];
  const float* wS  = (const float*)d_in[13];
  const float* bS  = (const float*)d_in[14];
  const float* gS  = (const float*)d_in[15];
  const float* beS = (const float*)d_in[16];

  char* ws = (char*)d_ws;
  size_t off = 0;
  auto carve = [&](size_t bytes) -> void* {
    void* p = ws + off;
    off += (bytes + 255) & ~(size_t)255;
    return p;
  };
  float* X        = (float*)carve((size_t)NPTS * CC * 4);       // 8.4 MB
  u16*   Xb       = (u16*)  carve((size_t)NPTS * CC * 2);       // 4.2 MB
  float* rr       = (float*)carve((size_t)NPTS * 4);            // 128 KB
  int*   idx      = (int*)  carve((size_t)NPTS * KK * 4);       // 2 MB
  u16*   wb0      = (u16*)  carve(8192 * 2);
  u16*   wb1      = (u16*)  carve(4096 * 2);
  u16*   wb2      = (u16*)  carve(4096 * 2);
  u16*   wbs      = (u16*)  carve(4096 * 2);
  u16*   y        = (u16*)  carve((size_t)MROWS * CC * 2);      // 67 MB
  u16*   ysc      = (u16*)  carve((size_t)NPTS * CC * 2);       // 4.2 MB
  float* partials = (float*)carve(512 * 128 * 4);               // 256 KB
  float* st0      = (float*)carve(128 * 4);
  float* st1      = (float*)carve(128 * 4);
  float* st2      = (float*)carve(128 * 4);
  float* stS      = (float*)carve(128 * 4);

  prep_k<<<NPTS / 256, 256, 0, stream>>>(F, X, Xb, rr);
  cvtw_k<<<80, 256, 0, stream>>>(w0, w1, w2, wS, wb0, wb1, wb2, wbs);
  knn_k<<<NB * (PP / 64), 256, 0, stream>>>(X, rr, idx);

  conv_k<128, true,  false><<<MROWS / 256, 256, 0, stream>>>(Xb, idx, wb0, b0, nullptr, y);
  stats_k<<<512, 256, 0, stream>>>(y, partials, MROWS);
  red_k<<<1, 256, 0, stream>>>(partials, g0, be0, st0, 1.f / (float)MROWS);

  conv_k<64, false, true><<<MROWS / 256, 256, 0, stream>>>(y, nullptr, wb1, b1, st0, y);
  stats_k<<<512, 256, 0, stream>>>(y, partials, MROWS);
  red_k<<<1, 256, 0, stream>>>(partials, g1, be1, st1, 1.f / (float)MROWS);

  conv_k<64, false, true><<<MROWS / 256, 256, 0, stream>>>(y, nullptr, wb2, b2, st1, y);
  stats_k<<<512, 256, 0, stream>>>(y, partials, MROWS);
  red_k<<<1, 256, 0, stream>>>(partials, g2, be2, st2, 1.f / (float)MROWS);

  conv_k<64, false, false><<<NPTS / 256, 256, 0, stream>>>(Xb, nullptr, wbs, bS, nullptr, ysc);
  stats_k<<<512, 256, 0, stream>>>(ysc, partials, NPTS);
  red_k<<<1, 256, 0, stream>>>(partials, gS, beS, stS, 1.f / (float)NPTS);

  final_k<<<NB * (PP / 64), 256, 0, stream>>>(y, ysc, st2, stS, (float*)d_out);
}